// Round 11
// baseline (616.003 us; speedup 1.0000x reference)
//
#include <hip/hip_runtime.h>
#include <hip/hip_bf16.h>

#define BB 4
#define TT 4096
#define HH 2048
#define NHH 16
#define VOC 100000
#define EE 1024
#define GG 4
#define BT (BB*TT)          // 16384 tokens, p = b*TT + t
#define NKEY (GG*HH)        // 8192
#define NTOT (NKEY+HH)      // 10240
#define NPART 32
#define TCV 48              // conv t-chunk (multiple of 3)

static constexpr float EPS_RMS = 1.1920929e-07f;
static constexpr float EPS_SC  = 1e-5f;
static constexpr float INV_SQRT_H = 0.02209708691207961f; // 1/sqrt(2048)

using f32x4 = __attribute__((ext_vector_type(4))) float;
using f32x2 = __attribute__((ext_vector_type(2))) float;
using s8v   = __attribute__((ext_vector_type(8))) short;
using gvoid = __attribute__((address_space(1))) const void;
using lvoid = __attribute__((address_space(3))) void;

__device__ __forceinline__ unsigned short f2bf(float f){
  union { __hip_bfloat16 h; unsigned short u; } cv;
  cv.h = __float2bfloat16(f);
  return cv.u;
}
__device__ __forceinline__ float bf2f(unsigned short u){
  union { float f; unsigned u; } cv;
  cv.u = ((unsigned)u) << 16;
  return cv.f;
}
__device__ __forceinline__ s8v pack8(float4 v0, float4 v1){
  s8v o;
  o[0]=(short)f2bf(v0.x); o[1]=(short)f2bf(v0.y); o[2]=(short)f2bf(v0.z); o[3]=(short)f2bf(v0.w);
  o[4]=(short)f2bf(v1.x); o[5]=(short)f2bf(v1.y); o[6]=(short)f2bf(v1.z); o[7]=(short)f2bf(v1.w);
  return o;
}

// ---- pack W (keys|value) into MFMA-fragment order (verified in R7):
// Bpk[(nb*32+kb)*512 + lane*8 + e] = W[nb*16+(lane&15)][kb*32+(lane>>4)*8+e]
__global__ __launch_bounds__(256) void convw_pack(const float* __restrict__ kW,
    const float* __restrict__ vW, unsigned short* __restrict__ Bpk){
  const int nb = blockIdx.x;                 // 0..639
  const int t = threadIdx.x, lane = t&63, q = t>>6;
  const int n = nb*16 + (lane&15);
  const float* src = (n < NKEY) ? (kW + (size_t)n*EE) : (vW + (size_t)(n-NKEY)*EE);
  #pragma unroll
  for (int i=0;i<8;i++){
    const int kb = q*8 + i;
    const int k0 = kb*32 + (lane>>4)*8;
    float4 v0 = *(const float4*)(src + k0);
    float4 v1 = *(const float4*)(src + k0 + 4);
    *(s8v*)(Bpk + (size_t)(nb*32 + kb)*512 + lane*8) = pack8(v0, v1);
  }
}

// ---------------- fused prep: hashed gather -> emb bf16 ; rq[p] ; hsbf [p][h] bf16 ----------------
__global__ __launch_bounds__(256) void prep_kern(const int* __restrict__ hids,
    const float* __restrict__ table, unsigned short* __restrict__ emb,
    const float* __restrict__ hs, float* __restrict__ rq,
    unsigned short* __restrict__ hsbf){
  const int p = blockIdx.x, tid = threadIdx.x;
  const int e = tid*4, head = e>>6, d = e&63;
  const long row = (long)hids[p*NHH + head] + (long)head*VOC;
  const float4 v = *(const float4*)(table + row*64 + d);
  ushort4 o; o.x=f2bf(v.x); o.y=f2bf(v.y); o.z=f2bf(v.z); o.w=f2bf(v.w);
  *(ushort4*)(emb + (size_t)p*EE + e) = o;
  const int b = p>>12, t = p&4095;
  const float* hrow = hs + ((size_t)t*BB + b)*HH;
  const int e8 = tid*8;
  float4 v0 = *(const float4*)(hrow+e8);
  float4 v1 = *(const float4*)(hrow+e8+4);
  *(s8v*)(hsbf + (size_t)p*HH + e8) = pack8(v0, v1);
  float s = v0.x*v0.x+v0.y*v0.y+v0.z*v0.z+v0.w*v0.w
          + v1.x*v1.x+v1.y*v1.y+v1.z*v1.z+v1.w*v1.w;
  #pragma unroll
  for (int of=32;of>=1;of>>=1) s += __shfl_xor(s,of);
  __shared__ float red[4];
  if ((tid&63)==0) red[tid>>6] = s;
  __syncthreads();
  if (tid==0){
    float tot = red[0]+red[1]+red[2]+red[3];
    rq[p] = rsqrtf(tot*(1.0f/HH) + EPS_RMS);
  }
}

// ======== 256x256 GEMM: A via LDS dbuf (2x32KB), B direct-from-global (fragment-packed) ========
__global__ __launch_bounds__(512, 2) void gemm8(
    const unsigned short* __restrict__ A, const unsigned short* __restrict__ Bpk,
    const float* __restrict__ key_b, const float* __restrict__ value_b,
    const float* __restrict__ n1w, const float* __restrict__ n2w,
    const unsigned short* __restrict__ hsbf, unsigned short* __restrict__ vlinb,
    f32x2* __restrict__ sdp, float* __restrict__ vsqp)
{
  __shared__ unsigned short sh[65536];   // 128 KiB: loop uses [0,32768) shorts (2 A-bufs); epilogue uses all
  const int tid = threadIdx.x, w = tid>>6, l = tid&63;
  const int wm = w>>2, wn = w&3;
  const int lg = l&15, lr = l>>4;
  // XCD-aware bijective swizzle (R5): 2560 blocks, 320/XCD = 8 contiguous tM rows, tN fast
  const int wg  = blockIdx.x;
  const int swz = (wg&7)*320 + (wg>>3);
  const int tM  = swz/40, tN = swz - tM*40;
  const int Mrow0 = tM*256, Nrow0 = tN*256;

  // A staging: conflict-free 3-bit chunk swizzle (R5): LDS linear, source chunk = (l&7) ^ (row&7)
  const int lp = l>>3, lcs = (l&7)^lp;
  const size_t aoffT = (size_t)(Mrow0 + w*16 + lp)*EE + lcs*8;
  // A ds_read: chunk' = (kk*4+lr) ^ (row&7), row&7 == lg&7
  const int c0 = lr ^ (lg&7);
  const unsigned aBase = (unsigned)(wm*8192 + lg*64);
  // B fragment offsets (packed global, verified layout from R7)
  const unsigned bof0 = (unsigned)(tN*16 + wn*4 + 0)*32u*512u + (unsigned)l*8u;
  const unsigned bof1 = (unsigned)(tN*16 + wn*4 + 1)*32u*512u + (unsigned)l*8u;
  const unsigned bof2 = (unsigned)(tN*16 + wn*4 + 2)*32u*512u + (unsigned)l*8u;
  const unsigned bof3 = (unsigned)(tN*16 + wn*4 + 3)*32u*512u + (unsigned)l*8u;

  f32x4 acc[8][4] = {};
  s8v aR0[4], aR1[4], bR0[4], bR1[4];

#define BAR() { asm volatile("" ::: "memory"); __builtin_amdgcn_s_barrier(); asm volatile("" ::: "memory"); }
#define WAITV(N) asm volatile("s_waitcnt vmcnt(" #N ")" ::: "memory")

#define STG_A(J, KT, SB) { \
    const unsigned short* s_ = A + aoffT + (J)*131072 + (KT)*64; \
    const unsigned d_ = (SB)*16384 + (J)*8192 + w*1024; \
    __builtin_amdgcn_global_load_lds((gvoid*)s_,        (lvoid*)(sh + d_),       16, 0, 0); \
    __builtin_amdgcn_global_load_lds((gvoid*)(s_+8192), (lvoid*)(sh + d_ + 512), 16, 0, 0); }
#define STAGE_A(KT, SB) { STG_A(0,KT,SB); STG_A(1,KT,SB); }

#define RD_A(CB, KK, MH, DST) { \
    const unsigned short* p_ = sh + (CB)*16384 + aBase; \
    const unsigned ck_ = (unsigned)((c0 ^ ((KK)<<2))<<3); \
    DST[0] = *(const s8v*)(p_ + ((MH)*4+0)*1024 + ck_); \
    DST[1] = *(const s8v*)(p_ + ((MH)*4+1)*1024 + ck_); \
    DST[2] = *(const s8v*)(p_ + ((MH)*4+2)*1024 + ck_); \
    DST[3] = *(const s8v*)(p_ + ((MH)*4+3)*1024 + ck_); }

#define GLB(KT, KK, DST) { \
    const unsigned short* q_ = Bpk + (unsigned)((KT)*2+(KK))*512u; \
    DST[0] = *(const s8v*)(q_ + bof0); \
    DST[1] = *(const s8v*)(q_ + bof1); \
    DST[2] = *(const s8v*)(q_ + bof2); \
    DST[3] = *(const s8v*)(q_ + bof3); }

#define MM(MH, AF, BF) { \
    __builtin_amdgcn_s_setprio(1); \
    _Pragma("unroll") \
    for (int mf=0; mf<4; mf++) \
      _Pragma("unroll") \
      for (int nf=0; nf<4; nf++) \
        acc[(MH)*4+mf][nf] = __builtin_amdgcn_mfma_f32_16x16x32_bf16(AF[mf], BF[nf], acc[(MH)*4+mf][nf], 0,0,0); \
    __builtin_amdgcn_s_setprio(0); }

#define TILE(CB, NB, KT0, KT1, DOST) { \
    BAR(); \
    if (DOST) STAGE_A(KT1, NB); \
    GLB(KT0, 1, bR1); \
    RD_A(CB,1,0,aR1); \
    MM(0, aR0, bR0); \
    RD_A(CB,0,1,aR0); \
    MM(0, aR1, bR1); \
    RD_A(CB,1,1,aR1); \
    MM(1, aR0, bR0); \
    WAITV(0); \
    BAR(); \
    GLB(KT1, 0, bR0); \
    RD_A(NB,0,0,aR0); \
    MM(1, aR1, bR1); }

#define TILE_LAST(CB, KT0) { \
    BAR(); \
    GLB(KT0, 1, bR1); \
    RD_A(CB,1,0,aR1); \
    MM(0, aR0, bR0); \
    RD_A(CB,0,1,aR0); \
    MM(0, aR1, bR1); \
    RD_A(CB,1,1,aR1); \
    MM(1, aR0, bR0); \
    MM(1, aR1, bR1); }

  // prologue: stage A tiles 0,1; preload tile-0 q00 fragments
  STAGE_A(0, 0);
  STAGE_A(1, 1);
  GLB(0, 0, bR0);
  WAITV(0);
  BAR();
  RD_A(0,0,0,aR0);

  #pragma unroll 1
  for (int i=0; i<7; i++){
    TILE(0, 1, 2*i,   2*i+1, true);
    TILE(1, 0, 2*i+1, 2*i+2, true);
  }
  TILE(0, 1, 14, 15, true);
  TILE_LAST(1, 15);

#undef STG_A
#undef STAGE_A
#undef RD_A
#undef GLB
#undef MM
#undef TILE
#undef TILE_LAST
#undef BAR
#undef WAITV

  __syncthreads();   // loop done; LDS free for epilogue

  // ---- epilogue ----
  const bool isK = (Nrow0 < NKEY);
  float bias[4], cw[4];
  #pragma unroll
  for (int nf=0; nf<4; nf++){
    const int n = Nrow0 + wn*64 + nf*16 + lg;
    if (isK){ bias[nf] = key_b[n]; cw[nf] = n1w[n]*n2w[n]; }
    else    { bias[nf] = value_b[n-NKEY]; cw[nf] = 0.f; }
  }

  if (isK){
    const int g = tN >> 3;
    const int slot = (tN&7)*4 + wn;
    const int colbase = (tN&7)*256;
    unsigned short* hsT = sh;                       // [0, 64KB): 128 rows x 256 cols bf16
    char* wreg = ((char*)sh) + 65536 + w*8192;      // [64KB,128KB): 8 KB per wave
    #pragma unroll
    for (int half=0; half<2; half++){
      // stage hsT for p-rows [Mrow0 + half*128, +128), coalesced + XOR-swizzled (R4-verified)
      #pragma unroll
      for (int pass=0; pass<8; pass++){
        const int r2 = pass*16 + (tid>>5);
        const int c8 = (tid&31)*8;
        const int p = Mrow0 + half*128 + r2;
        s8v wv = *(const s8v*)(hsbf + (size_t)p*HH + colbase + c8);
        *(s8v*)(hsT + r2*256 + (c8 ^ (((r2>>2)&3)<<4))) = wv;
      }
      __syncthreads();
      if (wm == half){
        #pragma unroll
        for (int pass2=0; pass2<2; pass2++){
          #pragma unroll
          for (int mfs=0; mfs<4; mfs++){
            const int mfa = pass2*4 + mfs;
            #pragma unroll
            for (int rr=0; rr<4; rr++){
              const int rowq = mfs*16 + lr*4 + rr;          // 0..63
              const int rowlh = pass2*64 + rowq;            // 0..127 within half
              float ssq=0.f, dt=0.f;
              #pragma unroll
              for (int nf=0; nf<4; nf++){
                const float c = acc[mfa][nf][rr] + bias[nf];
                const float hv = bf2f(hsT[rowlh*256 + wn*64 + ((nf^lr)<<4) + lg]);
                ssq += c*c;
                dt  += c * cw[nf] * hv;
              }
              f32x2 pr; pr[0]=ssq; pr[1]=dt;
              *(f32x2*)(wreg + rowq*128 + (((lg>>1) ^ (rowq&7))<<4) + ((lg&1)<<3)) = pr;
            }
          }
          // wave-private read-back: lane l sums row l across 16 lg slots
          {
            const int r = l;
            float ssq=0.f, dt=0.f;
            #pragma unroll
            for (int c=0; c<8; c++){
              f32x4 v = *(const f32x4*)(wreg + r*128 + ((c ^ (r&7))<<4));
              ssq += v[0] + v[2]; dt += v[1] + v[3];
            }
            const int p = Mrow0 + wm*128 + pass2*64 + r;
            f32x2 o2; o2[0]=ssq; o2[1]=dt;
            sdp[(size_t)(p*GG+g)*NPART + slot] = o2;
          }
        }
      }
      __syncthreads();
    }
  } else {
    const int slot = (tN-32)*4 + wn;
    const int h0 = Nrow0 - NKEY + wn*64;
    const int pbase = Mrow0 + wm*128;
    #pragma unroll
    for (int mfa=0; mfa<8; mfa++){
      #pragma unroll
      for (int rr=0; rr<4; rr++){
        const int p = pbase + mfa*16 + lr*4 + rr;
        float ssq=0.f;
        #pragma unroll
        for (int nf=0; nf<4; nf++){
          const float c = acc[mfa][nf][rr] + bias[nf];
          vlinb[(size_t)p*HH + h0 + nf*16 + lg] = f2bf(c);
          ssq += c*c;
        }
        #pragma unroll
        for (int o=1;o<16;o<<=1){ ssq += __shfl_xor(ssq,o); }
        if (lg==0) vsqp[(size_t)p*NPART + slot] = ssq;
      }
    }
  }
}

// ---------------- per-(token,group) scalars: gate + xn-scale a ----------------
__global__ __launch_bounds__(256) void scal_kern(const f32x2* __restrict__ sdp,
    const float* __restrict__ vsqp,
    const float* __restrict__ rq, float* __restrict__ gate, float* __restrict__ av){
  const int i = blockIdx.x*256 + threadIdx.x;   // BT*GG
  const int p = i>>2;
  float ss=0.f, dd=0.f, vv=0.f;
  const f32x2* sp = sdp + (size_t)i*NPART;
  #pragma unroll
  for (int j=0;j<NPART;j++){ f32x2 v = sp[j]; ss += v[0]; dd += v[1]; }
  #pragma unroll
  for (int j=0;j<NPART;j++){ vv += vsqp[(size_t)p*NPART+j]; }
  const float rk = rsqrtf(ss*(1.0f/HH) + EPS_RMS);
  const float gv = rk * rq[p] * dd * INV_SQRT_H;
  const float sgn = (gv>0.f)?1.f:((gv<0.f)?-1.f:0.f);
  const float g1 = sqrtf(fmaxf(fabsf(gv),1e-6f))*sgn;
  const float gt = 1.f/(1.f+__expf(-g1));
  const float msvl = vv*(1.0f/HH);
  const float a = gt * rsqrtf(gt*gt*msvl + EPS_SC);
  gate[i]=gt; av[i]=a;
}

// ---------------- conv: residue-mod-3 register window (vl and av), weights loaded once ----------------
__device__ __forceinline__ ushort4 ldrow(const unsigned short* __restrict__ v, int b, int t, int h0){
  if (t < 0){ ushort4 z; z.x=0;z.y=0;z.z=0;z.w=0; return z; }
  return *(const ushort4*)(v + (size_t)((b<<12)|t)*HH + h0);
}
__device__ __forceinline__ void ldav(const float* __restrict__ av, int b, int t, float* a){
  if (t < 0){ a[0]=0.f;a[1]=0.f;a[2]=0.f;a[3]=0.f; }
  else { const float4 x = *(const float4*)(av + (size_t)((b<<12)|t)*GG);
         a[0]=x.x;a[1]=x.y;a[2]=x.z;a[3]=x.w; }
}

__global__ __launch_bounds__(256) void conv2_kern(const unsigned short* __restrict__ vlinb,
    const float* __restrict__ gate, const float* __restrict__ av,
    const float* __restrict__ conv_w, const float* __restrict__ scw,
    float* __restrict__ out){
  const int bx = blockIdx.x;
  const int b  = blockIdx.y;
  const int t0 = (bx>>1)*TCV;
  const int h0 = (bx&1)*1024 + threadIdx.x*4;

  float cwv[4][4][4];
  float sc4[4][4];
  #pragma unroll
  for (int g=0; g<4; g++){
    #pragma unroll
    for (int j2=0; j2<4; j2++){
      const int c = g*HH + h0 + j2;
      const float4 wv = *(const float4*)(conv_w + (size_t)c*4);
      cwv[g][j2][0]=wv.x; cwv[g][j2][1]=wv.y; cwv[g][j2][2]=wv.z; cwv[g][j2][3]=wv.w;
      sc4[g][j2] = scw[c];
    }
  }

  #pragma unroll 1
  for (int r=0; r<3; r++){
    const int tf = t0 + r;
    ushort4 w0 = ldrow(vlinb, b, tf-9, h0);
    ushort4 w1 = ldrow(vlinb, b, tf-6, h0);
    ushort4 w2 = ldrow(vlinb, b, tf-3, h0);
    ushort4 w3; w3.x=0;w3.y=0;w3.z=0;w3.w=0;
    float a0[4],a1[4],a2[4],a3[4];
    ldav(av, b, tf-9, a0); ldav(av, b, tf-6, a1); ldav(av, b, tf-3, a2);
    #pragma unroll
    for (int j=0; j<16; j++){
      const int t = tf + 3*j;
      if (t < TT){
        const int p = (b<<12)|t;
        w3 = *(const ushort4*)(vlinb + (size_t)p*HH + h0);
        ldav(av, b, t, a3);
        float gt4[4];
        { const float4 xx = *(const float4*)(gate + (size_t)p*GG);
          gt4[0]=xx.x; gt4[1]=xx.y; gt4[2]=xx.z; gt4[3]=xx.w; }
        float v0[4],v1[4],v2[4],v3[4];
        v0[0]=bf2f(w0.x); v0[1]=bf2f(w0.y); v0[2]=bf2f(w0.z); v0[3]=bf2f(w0.w);
        v1[0]=bf2f(w1.x); v1[1]=bf2f(w1.y); v1[2]=bf2f(w1.z); v1[3]=bf2f(w1.w);
        v2[0]=bf2f(w2.x); v2[1]=bf2f(w2.y); v2[2]=bf2f(w2.z); v2[3]=bf2f(w2.w);
        v3[0]=bf2f(w3.x); v3[1]=bf2f(w3.y); v3[2]=bf2f(w3.z); v3[3]=bf2f(w3.w);
        float4 ov;
        float res[4];
        #pragma unroll
        for (int j2=0; j2<4; j2++){
          float acc = 0.f;
          #pragma unroll
          for (int g=0; g<4; g++){
            float y = cwv[g][j2][0]*a0[g]*v0[j2]
                    + cwv[g][j2][1]*a1[g]*v1[j2]
                    + cwv[g][j2][2]*a2[g]*v2[j2]
                    + cwv[g][j2][3]*a3[g]*v3[j2];
            y *= sc4[g][j2];
            const float sy = y * (1.f/(1.f+__expf(-y)));
            acc += gt4[g]*v3[j2] + sy;
          }
          res[j2] = acc*0.25f;
        }
        ov.x=res[0]; ov.y=res[1]; ov.z=res[2]; ov.w=res[3];
        *(float4*)(out + ((size_t)t*BB + b)*HH + h0) = ov;
      }
      w0=w1; w1=w2; w2=w3;
      #pragma unroll
      for (int g=0; g<4; g++){ a0[g]=a1[g]; a1[g]=a2[g]; a2[g]=a3[g]; }
    }
  }
}

extern "C" void kernel_launch(void* const* d_in, const int* in_sizes, int n_in,
                              void* d_out, int out_size, void* d_ws, size_t ws_size,
                              hipStream_t stream){
  (void)in_sizes; (void)n_in; (void)out_size; (void)ws_size;
  const float* hs    = (const float*)d_in[0];
  const int*   hids  = (const int*)d_in[1];
  const float* table = (const float*)d_in[2];
  const float* keyW  = (const float*)d_in[3];
  const float* keyB  = (const float*)d_in[4];
  const float* valW  = (const float*)d_in[5];
  const float* valB  = (const float*)d_in[6];
  const float* n1w   = (const float*)d_in[7];
  const float* n2w   = (const float*)d_in[8];
  const float* scw   = (const float*)d_in[9];
  const float* convw = (const float*)d_in[10];
  float* out = (float*)d_out;

  char* ws = (char*)d_ws;
  size_t off = 0;
  unsigned short* emb   = (unsigned short*)(ws+off); off += (size_t)BT*EE*2;      // 33.5 MB
  unsigned short* Bpk   = (unsigned short*)(ws+off); off += (size_t)NTOT*EE*2;    // 21 MB
  unsigned short* vlinb = (unsigned short*)(ws+off); off += (size_t)BT*HH*2;      // 67 MB
  unsigned short* hsbf  = (unsigned short*)(ws+off); off += (size_t)BT*HH*2;      // 67 MB
  f32x2* sdp    = (f32x2*)(ws+off); off += (size_t)BT*GG*NPART*8;                 // 16.8 MB
  float* vsqp   = (float*)(ws+off); off += (size_t)BT*NPART*4;                    // 2.1 MB
  float* rq     = (float*)(ws+off); off += (size_t)BT*4;
  float* gate   = (float*)(ws+off); off += (size_t)BT*GG*4;
  float* av     = (float*)(ws+off); off += (size_t)BT*GG*4;

  convw_pack<<<NTOT/16, 256, 0, stream>>>(keyW, valW, Bpk);
  prep_kern<<<BT, 256, 0, stream>>>(hids, table, emb, hs, rq, hsbf);
  gemm8<<<2560, 512, 0, stream>>>(emb, Bpk, keyB, valB, n1w, n2w, hsbf, vlinb, sdp, vsqp);
  scal_kern<<<(BT*GG)/256, 256, 0, stream>>>(sdp, vsqp, rq, gate, av);
  dim3 cg(((TT + TCV - 1)/TCV)*2, BB);  // 172 x 4
  conv2_kern<<<cg, 256, 0, stream>>>(vlinb, gate, av, convw, scw, out);
}

// Round 12
// 542.295 us; speedup vs baseline: 1.1359x; 1.1359x over previous
//
#include <hip/hip_runtime.h>
#include <hip/hip_bf16.h>

#define BB 4
#define TT 4096
#define HH 2048
#define NHH 16
#define VOC 100000
#define EE 1024
#define GG 4
#define BT (BB*TT)          // 16384 tokens, p = b*TT + t
#define NKEY (GG*HH)        // 8192
#define NTOT (NKEY+HH)      // 10240
#define NPART 32
#define TCV 48              // conv t-chunk (multiple of 3)

static constexpr float EPS_RMS = 1.1920929e-07f;
static constexpr float EPS_SC  = 1e-5f;
static constexpr float INV_SQRT_H = 0.02209708691207961f; // 1/sqrt(2048)

using f32x4 = __attribute__((ext_vector_type(4))) float;
using f32x2 = __attribute__((ext_vector_type(2))) float;
using s8v   = __attribute__((ext_vector_type(8))) short;
using gvoid = __attribute__((address_space(1))) const void;
using lvoid = __attribute__((address_space(3))) void;

__device__ __forceinline__ unsigned short f2bf(float f){
  union { __hip_bfloat16 h; unsigned short u; } cv;
  cv.h = __float2bfloat16(f);
  return cv.u;
}
__device__ __forceinline__ float bf2f(unsigned short u){
  union { float f; unsigned u; } cv;
  cv.u = ((unsigned)u) << 16;
  return cv.f;
}
__device__ __forceinline__ s8v pack8(float4 v0, float4 v1){
  s8v o;
  o[0]=(short)f2bf(v0.x); o[1]=(short)f2bf(v0.y); o[2]=(short)f2bf(v0.z); o[3]=(short)f2bf(v0.w);
  o[4]=(short)f2bf(v1.x); o[5]=(short)f2bf(v1.y); o[6]=(short)f2bf(v1.z); o[7]=(short)f2bf(v1.w);
  return o;
}

// ---------------- weight convert: [keyW | valueW] -> bf16 [10240,1024] ----------------
__global__ __launch_bounds__(256) void convw_kern(const float* __restrict__ kW,
    const float* __restrict__ vW, unsigned short* __restrict__ Wc){
  const long idx  = (long)blockIdx.x*256 + threadIdx.x;
  const long base = idx*4;
  const long KN   = (long)NKEY*EE;
  float4 v;
  if (base < KN) v = *(const float4*)(kW + base);
  else           v = *(const float4*)(vW + (base - KN));
  ushort4 o; o.x=f2bf(v.x); o.y=f2bf(v.y); o.z=f2bf(v.z); o.w=f2bf(v.w);
  *(ushort4*)(Wc + base) = o;
}

// ---------------- fused prep: hashed gather -> emb bf16 ; rq[p] ; hsbf [p][h] bf16 ----------------
__global__ __launch_bounds__(256) void prep_kern(const int* __restrict__ hids,
    const float* __restrict__ table, unsigned short* __restrict__ emb,
    const float* __restrict__ hs, float* __restrict__ rq,
    unsigned short* __restrict__ hsbf){
  const int p = blockIdx.x, tid = threadIdx.x;
  const int e = tid*4, head = e>>6, d = e&63;
  const long row = (long)hids[p*NHH + head] + (long)head*VOC;
  const float4 v = *(const float4*)(table + row*64 + d);
  ushort4 o; o.x=f2bf(v.x); o.y=f2bf(v.y); o.z=f2bf(v.z); o.w=f2bf(v.w);
  *(ushort4*)(emb + (size_t)p*EE + e) = o;
  const int b = p>>12, t = p&4095;
  const float* hrow = hs + ((size_t)t*BB + b)*HH;
  const int e8 = tid*8;
  float4 v0 = *(const float4*)(hrow+e8);
  float4 v1 = *(const float4*)(hrow+e8+4);
  *(s8v*)(hsbf + (size_t)p*HH + e8) = pack8(v0, v1);
  float s = v0.x*v0.x+v0.y*v0.y+v0.z*v0.z+v0.w*v0.w
          + v1.x*v1.x+v1.y*v1.y+v1.z*v1.z+v1.w*v1.w;
  #pragma unroll
  for (int of=32;of>=1;of>>=1) s += __shfl_xor(s,of);
  __shared__ float red[4];
  if ((tid&63)==0) red[tid>>6] = s;
  __syncthreads();
  if (tid==0){
    float tot = red[0]+red[1]+red[2]+red[3];
    rq[p] = rsqrtf(tot*(1.0f/HH) + EPS_RMS);
  }
}

// ======== 256x256 GEMM, m201-style quadrant-phased 8-phase, counted vmcnt(4) ========
// Per phase: ALL 8 waves compute one 128x128 C-quadrant (wave = 64 rows x 32 cols).
// Stage order Ah0@P0,Bh0@P1,Bh1@P2,Ah1@P3 matches first-use stagger -> counted waits.
__global__ __launch_bounds__(512, 2) void gemm8(
    const unsigned short* __restrict__ A, const unsigned short* __restrict__ Bw,
    const float* __restrict__ key_b, const float* __restrict__ value_b,
    const float* __restrict__ n1w, const float* __restrict__ n2w,
    const unsigned short* __restrict__ hsbf, unsigned short* __restrict__ vlinb,
    f32x2* __restrict__ sdp, float* __restrict__ vsqp)
{
  __shared__ unsigned short sh[65536];   // 128 KiB: [2 bufs][A 32KB | B 32KB], halves of 16KB
  const int tid = threadIdx.x, w = tid>>6, l = tid&63;
  const int wr = w>>2, wc = w&3;         // 64-row band within quadrant / 32-col band
  const int lg = l&15, lr = l>>4;
  // XCD-aware bijective swizzle: 2560 blocks, 320/XCD = 8 contiguous tM rows
  const int wg  = blockIdx.x;
  const int swz = (wg&7)*320 + (wg>>3);
  const int tM  = swz/40, tN = swz - tM*40;
  const int Mrow0 = tM*256, Nrow0 = tN*256;

  // staging (R4-verified): conflict-free 3-bit chunk swizzle, source chunk = (l&7)^(row&7)
  const int lp = l>>3, lcs = (l&7)^lp;
  const size_t aoffT = (size_t)(Mrow0 + w*16 + lp)*EE + lcs*8;
  const size_t boffT = (size_t)(Nrow0 + w*16 + lp)*EE + lcs*8;
  // ds_read: chunk' = (kk*4+lr) ^ (row&7), row&7 == lg&7
  const int c0 = lr ^ (lg&7);
  const unsigned ck0 = (unsigned)(c0<<3);         // shorts
  const unsigned ck1 = (unsigned)((c0^4)<<3);
  const unsigned aBase = (unsigned)(wr*4096 + lg*64);            // + QR*8192 + mf*1024
  const unsigned bBase = 16384u + (unsigned)(wc*2048 + lg*64);   // + QC*8192 + nf*1024

  f32x4 acc[4][4][2] = {};   // [quad=QR*2+QC][mf][nf]
  s8v aK0[4], aK1[4];        // A frags for current row-half, kk=0/1
  s8v b0[2][2], b1[2][2];    // B frags col-half 0/1: [kk][nf]

#define BAR() { asm volatile("" ::: "memory"); __builtin_amdgcn_s_barrier(); asm volatile("" ::: "memory"); }

#define STAGEH(ISB, H, KT, SB) { \
    const unsigned short* s0_ = ((ISB) ? (Bw + boffT) : (A + aoffT)) + (H)*131072 + (KT)*64; \
    const unsigned d0_ = (SB)*32768 + (ISB)*16384 + (H)*8192 + w*1024; \
    __builtin_amdgcn_global_load_lds((gvoid*)s0_,        (lvoid*)(sh + d0_),       16, 0, 0); \
    __builtin_amdgcn_global_load_lds((gvoid*)(s0_+8192), (lvoid*)(sh + d0_ + 512), 16, 0, 0); \
  }

#define RD_AQ(CB, QR) { \
    const unsigned short* p_ = sh + (CB)*32768 + (QR)*8192 + aBase; \
    aK0[0]=*(const s8v*)(p_+0*1024+ck0); aK0[1]=*(const s8v*)(p_+1*1024+ck0); \
    aK0[2]=*(const s8v*)(p_+2*1024+ck0); aK0[3]=*(const s8v*)(p_+3*1024+ck0); \
    aK1[0]=*(const s8v*)(p_+0*1024+ck1); aK1[1]=*(const s8v*)(p_+1*1024+ck1); \
    aK1[2]=*(const s8v*)(p_+2*1024+ck1); aK1[3]=*(const s8v*)(p_+3*1024+ck1); }

#define RD_BQ(CB, QC, B) { \
    const unsigned short* p_ = sh + (CB)*32768 + (QC)*8192 + bBase; \
    B[0][0]=*(const s8v*)(p_+0*1024+ck0); B[0][1]=*(const s8v*)(p_+1*1024+ck0); \
    B[1][0]=*(const s8v*)(p_+0*1024+ck1); B[1][1]=*(const s8v*)(p_+1*1024+ck1); }

#define MMQ(QR, QC, B) { \
    __builtin_amdgcn_s_setprio(1); \
    _Pragma("unroll") \
    for (int mf=0; mf<4; mf++){ \
      acc[(QR)*2+(QC)][mf][0] = __builtin_amdgcn_mfma_f32_16x16x32_bf16(aK0[mf], B[0][0], acc[(QR)*2+(QC)][mf][0], 0,0,0); \
      acc[(QR)*2+(QC)][mf][1] = __builtin_amdgcn_mfma_f32_16x16x32_bf16(aK0[mf], B[0][1], acc[(QR)*2+(QC)][mf][1], 0,0,0); \
    } \
    _Pragma("unroll") \
    for (int mf=0; mf<4; mf++){ \
      acc[(QR)*2+(QC)][mf][0] = __builtin_amdgcn_mfma_f32_16x16x32_bf16(aK1[mf], B[1][0], acc[(QR)*2+(QC)][mf][0], 0,0,0); \
      acc[(QR)*2+(QC)][mf][1] = __builtin_amdgcn_mfma_f32_16x16x32_bf16(aK1[mf], B[1][1], acc[(QR)*2+(QC)][mf][1], 0,0,0); \
    } \
    __builtin_amdgcn_s_setprio(0); }

#define LGKM0() { asm volatile("s_waitcnt lgkmcnt(0)" ::: "memory"); __builtin_amdgcn_sched_barrier(0); }

#define PH0(CB, NB, KT1, DOST, VM) { \
    RD_AQ(CB, 0); RD_BQ(CB, 0, b0); \
    if (DOST) STAGEH(0,0,KT1,NB); \
    asm volatile("s_waitcnt lgkmcnt(8)" ::: "memory"); \
    BAR(); LGKM0(); \
    MMQ(0,0,b0); \
    VM; BAR(); }

#define PH1(CB, NB, KT1, DOST, VM) { \
    RD_BQ(CB, 1, b1); \
    if (DOST) STAGEH(1,0,KT1,NB); \
    BAR(); LGKM0(); \
    MMQ(0,1,b1); \
    VM; BAR(); }

#define PH2(CB, NB, KT1, DOST) { \
    RD_AQ(CB, 1); \
    if (DOST) STAGEH(1,1,KT1,NB); \
    BAR(); LGKM0(); \
    MMQ(1,0,b0); \
    BAR(); }

#define PH3(CB, NB, KT1, DOST, VM) { \
    if (DOST) STAGEH(0,1,KT1,NB); \
    BAR(); \
    MMQ(1,1,b1); \
    VM; BAR(); }

#define VM4 asm volatile("s_waitcnt vmcnt(4)" ::: "memory")
#define VM2 asm volatile("s_waitcnt vmcnt(2)" ::: "memory")
#define VM0 asm volatile("s_waitcnt vmcnt(0)" ::: "memory")
#define VMN (void)0

#define TILE_STD(CB, NB, KT1) { \
    PH0(CB, NB, KT1, 1, VM4); \
    PH1(CB, NB, KT1, 1, VM4); \
    PH2(CB, NB, KT1, 1); \
    PH3(CB, NB, KT1, 1, VM4); }

  // prologue: stage tile 0 (consumption order Ah0,Bh0,Bh1,Ah1); wait first two halves
  STAGEH(0,0,0,0); STAGEH(1,0,0,0); STAGEH(1,1,0,0); STAGEH(0,1,0,0);
  VM4;
  BAR();

  #pragma unroll 1
  for (int i=0; i<7; i++){
    TILE_STD(0, 1, 2*i+1);
    TILE_STD(1, 0, 2*i+2);
  }
  TILE_STD(0, 1, 15);              // tile 14, stages tile 15
  // tile 15: no staging; tail-counted waits
  PH0(1, 0, 0, 0, VM2);
  PH1(1, 0, 0, 0, VM0);
  PH2(1, 0, 0, 0);
  PH3(1, 0, 0, 0, VMN);

#undef BAR
#undef STAGEH
#undef RD_AQ
#undef RD_BQ
#undef MMQ
#undef LGKM0
#undef PH0
#undef PH1
#undef PH2
#undef PH3
#undef VM4
#undef VM2
#undef VM0
#undef VMN
#undef TILE_STD

  __syncthreads();   // loop done; LDS free for epilogue

  // ---- epilogue ----
  const bool isK = (Nrow0 < NKEY);
  float bias[2][2], cw[2][2]; int ncol[2][2];
  #pragma unroll
  for (int QC=0; QC<2; QC++){
    #pragma unroll
    for (int nf=0; nf<2; nf++){
      const int n = Nrow0 + QC*128 + wc*32 + nf*16 + lg;
      ncol[QC][nf] = QC*128 + wc*32 + nf*16 + lg;
      if (isK){ bias[QC][nf] = key_b[n]; cw[QC][nf] = n1w[n]*n2w[n]; }
      else    { bias[QC][nf] = value_b[n-NKEY]; cw[QC][nf] = 0.f; }
    }
  }

  if (isK){
    const int g = tN >> 3;
    const int slot = (tN&7)*4 + wc;
    const int colbase = (tN&7)*256;
    unsigned short* hsT = sh;                       // [0,64KB): 128 rows x 256 cols bf16
    char* wreg = ((char*)sh) + 65536 + w*8192;      // [64KB,128KB): 8 KB per wave
    #pragma unroll
    for (int QR=0; QR<2; QR++){
      // stage hsT for p-rows [Mrow0+QR*128, +128), coalesced + XOR-swizzled (R4-verified)
      #pragma unroll
      for (int pass=0; pass<8; pass++){
        const int r2 = pass*16 + (tid>>5);
        const int c8 = (tid&31)*8;
        const int p = Mrow0 + QR*128 + r2;
        s8v wv = *(const s8v*)(hsbf + (size_t)p*HH + colbase + c8);
        *(s8v*)(hsT + r2*256 + (c8 ^ (((r2>>2)&3)<<4))) = wv;
      }
      __syncthreads();
      #pragma unroll
      for (int mf=0; mf<4; mf++){
        #pragma unroll
        for (int rr=0; rr<4; rr++){
          const int rowq = mf*16 + lr*4 + rr;      // 0..63 within wave band
          const int rowh = wr*64 + rowq;           // 0..127 within half
          float ssq=0.f, dt=0.f;
          #pragma unroll
          for (int QC=0; QC<2; QC++){
            #pragma unroll
            for (int nf=0; nf<2; nf++){
              const float c = acc[QR*2+QC][mf][nf][rr] + bias[QC][nf];
              const float hv = bf2f(hsT[rowh*256 + (ncol[QC][nf] ^ (lr<<4))]);
              ssq += c*c;
              dt  += c * cw[QC][nf] * hv;
            }
          }
          f32x2 pr; pr[0]=ssq; pr[1]=dt;
          *(f32x2*)(wreg + rowq*128 + (((lg>>1) ^ (rowq&7))<<4) + ((lg&1)<<3)) = pr;
        }
      }
      // wave-private readback: lane l sums row l across 16 lg slots
      {
        const int r = l;
        float ssq=0.f, dt=0.f;
        #pragma unroll
        for (int c=0; c<8; c++){
          f32x4 v = *(const f32x4*)(wreg + r*128 + ((c ^ (r&7))<<4));
          ssq += v[0] + v[2]; dt += v[1] + v[3];
        }
        const int p = Mrow0 + QR*128 + wr*64 + r;
        f32x2 o2; o2[0]=ssq; o2[1]=dt;
        sdp[(size_t)(p*GG+g)*NPART + slot] = o2;
      }
      __syncthreads();   // before next half overwrites hsT
    }
  } else {
    const int slot = (tN-32)*4 + wc;
    const int hbase = Nrow0 - NKEY;
    #pragma unroll
    for (int QR=0; QR<2; QR++){
      #pragma unroll
      for (int mf=0; mf<4; mf++){
        #pragma unroll
        for (int rr=0; rr<4; rr++){
          const int p = Mrow0 + QR*128 + wr*64 + mf*16 + lr*4 + rr;
          float ssq=0.f;
          #pragma unroll
          for (int QC=0; QC<2; QC++){
            #pragma unroll
            for (int nf=0; nf<2; nf++){
              const float c = acc[QR*2+QC][mf][nf][rr] + bias[QC][nf];
              vlinb[(size_t)p*HH + hbase + ncol[QC][nf]] = f2bf(c);
              ssq += c*c;
            }
          }
          #pragma unroll
          for (int o=1;o<16;o<<=1){ ssq += __shfl_xor(ssq,o); }
          if (lg==0) vsqp[(size_t)p*NPART + slot] = ssq;
        }
      }
    }
  }
}

// ---------------- per-(token,group) scalars: gate + xn-scale a ----------------
__global__ __launch_bounds__(256) void scal_kern(const f32x2* __restrict__ sdp,
    const float* __restrict__ vsqp,
    const float* __restrict__ rq, float* __restrict__ gate, float* __restrict__ av){
  const int i = blockIdx.x*256 + threadIdx.x;   // BT*GG
  const int p = i>>2;
  float ss=0.f, dd=0.f, vv=0.f;
  const f32x2* sp = sdp + (size_t)i*NPART;
  #pragma unroll
  for (int j=0;j<NPART;j++){ f32x2 v = sp[j]; ss += v[0]; dd += v[1]; }
  #pragma unroll
  for (int j=0;j<NPART;j++){ vv += vsqp[(size_t)p*NPART+j]; }
  const float rk = rsqrtf(ss*(1.0f/HH) + EPS_RMS);
  const float gv = rk * rq[p] * dd * INV_SQRT_H;
  const float sgn = (gv>0.f)?1.f:((gv<0.f)?-1.f:0.f);
  const float g1 = sqrtf(fmaxf(fabsf(gv),1e-6f))*sgn;
  const float gt = 1.f/(1.f+__expf(-g1));
  const float msvl = vv*(1.0f/HH);
  const float a = gt * rsqrtf(gt*gt*msvl + EPS_SC);
  gate[i]=gt; av[i]=a;
}

// ---------------- conv: residue-mod-3 register window (vl and av), weights loaded once ----------------
__device__ __forceinline__ ushort4 ldrow(const unsigned short* __restrict__ v, int b, int t, int h0){
  if (t < 0){ ushort4 z; z.x=0;z.y=0;z.z=0;z.w=0; return z; }
  return *(const ushort4*)(v + (size_t)((b<<12)|t)*HH + h0);
}
__device__ __forceinline__ void ldav(const float* __restrict__ av, int b, int t, float* a){
  if (t < 0){ a[0]=0.f;a[1]=0.f;a[2]=0.f;a[3]=0.f; }
  else { const float4 x = *(const float4*)(av + (size_t)((b<<12)|t)*GG);
         a[0]=x.x;a[1]=x.y;a[2]=x.z;a[3]=x.w; }
}

__global__ __launch_bounds__(256) void conv2_kern(const unsigned short* __restrict__ vlinb,
    const float* __restrict__ gate, const float* __restrict__ av,
    const float* __restrict__ conv_w, const float* __restrict__ scw,
    float* __restrict__ out){
  const int bx = blockIdx.x;
  const int b  = blockIdx.y;
  const int t0 = (bx>>1)*TCV;
  const int h0 = (bx&1)*1024 + threadIdx.x*4;

  float cwv[4][4][4];
  float sc4[4][4];
  #pragma unroll
  for (int g=0; g<4; g++){
    #pragma unroll
    for (int j2=0; j2<4; j2++){
      const int c = g*HH + h0 + j2;
      const float4 wv = *(const float4*)(conv_w + (size_t)c*4);
      cwv[g][j2][0]=wv.x; cwv[g][j2][1]=wv.y; cwv[g][j2][2]=wv.z; cwv[g][j2][3]=wv.w;
      sc4[g][j2] = scw[c];
    }
  }

  #pragma unroll 1
  for (int r=0; r<3; r++){
    const int tf = t0 + r;
    ushort4 w0 = ldrow(vlinb, b, tf-9, h0);
    ushort4 w1 = ldrow(vlinb, b, tf-6, h0);
    ushort4 w2 = ldrow(vlinb, b, tf-3, h0);
    ushort4 w3; w3.x=0;w3.y=0;w3.z=0;w3.w=0;
    float a0[4],a1[4],a2[4],a3[4];
    ldav(av, b, tf-9, a0); ldav(av, b, tf-6, a1); ldav(av, b, tf-3, a2);
    #pragma unroll
    for (int j=0; j<16; j++){
      const int t = tf + 3*j;
      if (t < TT){
        const int p = (b<<12)|t;
        w3 = *(const ushort4*)(vlinb + (size_t)p*HH + h0);
        ldav(av, b, t, a3);
        float gt4[4];
        { const float4 xx = *(const float4*)(gate + (size_t)p*GG);
          gt4[0]=xx.x; gt4[1]=xx.y; gt4[2]=xx.z; gt4[3]=xx.w; }
        float v0[4],v1[4],v2[4],v3[4];
        v0[0]=bf2f(w0.x); v0[1]=bf2f(w0.y); v0[2]=bf2f(w0.z); v0[3]=bf2f(w0.w);
        v1[0]=bf2f(w1.x); v1[1]=bf2f(w1.y); v1[2]=bf2f(w1.z); v1[3]=bf2f(w1.w);
        v2[0]=bf2f(w2.x); v2[1]=bf2f(w2.y); v2[2]=bf2f(w2.z); v2[3]=bf2f(w2.w);
        v3[0]=bf2f(w3.x); v3[1]=bf2f(w3.y); v3[2]=bf2f(w3.z); v3[3]=bf2f(w3.w);
        float4 ov;
        float res[4];
        #pragma unroll
        for (int j2=0; j2<4; j2++){
          float acc = 0.f;
          #pragma unroll
          for (int g=0; g<4; g++){
            float y = cwv[g][j2][0]*a0[g]*v0[j2]
                    + cwv[g][j2][1]*a1[g]*v1[j2]
                    + cwv[g][j2][2]*a2[g]*v2[j2]
                    + cwv[g][j2][3]*a3[g]*v3[j2];
            y *= sc4[g][j2];
            const float sy = y * (1.f/(1.f+__expf(-y)));
            acc += gt4[g]*v3[j2] + sy;
          }
          res[j2] = acc*0.25f;
        }
        ov.x=res[0]; ov.y=res[1]; ov.z=res[2]; ov.w=res[3];
        *(float4*)(out + ((size_t)t*BB + b)*HH + h0) = ov;
      }
      w0=w1; w1=w2; w2=w3;
      #pragma unroll
      for (int g=0; g<4; g++){ a0[g]=a1[g]; a1[g]=a2[g]; a2[g]=a3[g]; }
    }
  }
}

extern "C" void kernel_launch(void* const* d_in, const int* in_sizes, int n_in,
                              void* d_out, int out_size, void* d_ws, size_t ws_size,
                              hipStream_t stream){
  (void)in_sizes; (void)n_in; (void)out_size; (void)ws_size;
  const float* hs    = (const float*)d_in[0];
  const int*   hids  = (const int*)d_in[1];
  const float* table = (const float*)d_in[2];
  const float* keyW  = (const float*)d_in[3];
  const float* keyB  = (const float*)d_in[4];
  const float* valW  = (const float*)d_in[5];
  const float* valB  = (const float*)d_in[6];
  const float* n1w   = (const float*)d_in[7];
  const float* n2w   = (const float*)d_in[8];
  const float* scw   = (const float*)d_in[9];
  const float* convw = (const float*)d_in[10];
  float* out = (float*)d_out;

  char* ws = (char*)d_ws;
  size_t off = 0;
  unsigned short* emb   = (unsigned short*)(ws+off); off += (size_t)BT*EE*2;      // 33.5 MB
  unsigned short* Wc    = (unsigned short*)(ws+off); off += (size_t)NTOT*EE*2;    // 21 MB
  unsigned short* vlinb = (unsigned short*)(ws+off); off += (size_t)BT*HH*2;      // 67 MB
  unsigned short* hsbf  = (unsigned short*)(ws+off); off += (size_t)BT*HH*2;      // 67 MB
  f32x2* sdp    = (f32x2*)(ws+off); off += (size_t)BT*GG*NPART*8;                 // 16.8 MB
  float* vsqp   = (float*)(ws+off); off += (size_t)BT*NPART*4;                    // 2.1 MB
  float* rq     = (float*)(ws+off); off += (size_t)BT*4;
  float* gate   = (float*)(ws+off); off += (size_t)BT*GG*4;
  float* av     = (float*)(ws+off); off += (size_t)BT*GG*4;

  convw_kern<<<(NTOT*EE/4)/256, 256, 0, stream>>>(keyW, valW, Wc);
  prep_kern<<<BT, 256, 0, stream>>>(hids, table, emb, hs, rq, hsbf);
  gemm8<<<2560, 512, 0, stream>>>(emb, Wc, keyB, valB, n1w, n2w, hsbf, vlinb, sdp, vsqp);
  scal_kern<<<(BT*GG)/256, 256, 0, stream>>>(sdp, vsqp, rq, gate, av);
  dim3 cg(((TT + TCV - 1)/TCV)*2, BB);  // 172 x 4
  conv2_kern<<<cg, 256, 0, stream>>>(vlinb, gate, av, convw, scw, out);
}